// Round 1
// baseline (715.893 us; speedup 1.0000x reference)
//
#include <hip/hip_runtime.h>

#define N_D 128
#define HALF_D 64   // float2 elements per row

// ---------------- CSR build phase ----------------

__global__ void count_rows(const int* __restrict__ row, int* __restrict__ counts, int E) {
    int e = blockIdx.x * blockDim.x + threadIdx.x;
    if (e < E) atomicAdd(&counts[row[e]], 1);
}

// per-block inclusive scan of 1024 counts -> offsets[i+1] (local), blockSums[b]=total
__global__ void scan_local(const int* __restrict__ counts, int* __restrict__ offsets,
                           int* __restrict__ blockSums, int N) {
    __shared__ int s[1024];
    int t = threadIdx.x;
    int i = blockIdx.x * 1024 + t;
    int x = (i < N) ? counts[i] : 0;
    s[t] = x;
    __syncthreads();
    for (int d = 1; d < 1024; d <<= 1) {
        int v = (t >= d) ? s[t - d] : 0;
        __syncthreads();
        if (t >= d) s[t] += v;
        __syncthreads();
    }
    if (i < N) offsets[i + 1] = s[t];
    if (t == 1023) blockSums[blockIdx.x] = s[1023];
}

// single block: exclusive scan of up to 128 block sums, in place
__global__ void scan_blocksums(int* __restrict__ blockSums, int nb) {
    __shared__ int s[128];
    int t = threadIdx.x;
    int x = (t < nb) ? blockSums[t] : 0;
    s[t] = x;
    __syncthreads();
    for (int d = 1; d < 128; d <<= 1) {
        int v = (t >= d) ? s[t - d] : 0;
        __syncthreads();
        if (t >= d) s[t] += v;
        __syncthreads();
    }
    if (t < nb) blockSums[t] = s[t] - x;  // exclusive
}

// add block offsets; produce final offsets[] and per-row scatter cursor[]
__global__ void finalize_offsets(const int* __restrict__ counts, int* __restrict__ offsets,
                                 const int* __restrict__ blockSums, int* __restrict__ cursor, int N) {
    int i = blockIdx.x * blockDim.x + threadIdx.x;
    if (i >= N) return;
    int off = blockSums[i >> 10];
    int incl = offsets[i + 1] + off;
    offsets[i + 1] = incl;
    cursor[i] = incl - counts[i];   // exclusive prefix = row start
    if (i == 0) offsets[0] = 0;
}

// bucket edges by row: sorted[p] = (col, bitcast(val))
__global__ void scatter_edges(const int* __restrict__ row, const int* __restrict__ col,
                              const float* __restrict__ val, int* __restrict__ cursor,
                              int2* __restrict__ sorted, int E) {
    int e = blockIdx.x * blockDim.x + threadIdx.x;
    if (e < E) {
        int r = row[e];
        int p = atomicAdd(&cursor[r], 1);
        sorted[p] = make_int2(col[e], __float_as_int(val[e]));
    }
}

// ---------------- aggregation: one row per 64-thread wave ----------------
// lane t owns float2 (columns 2t, 2t+1); per edge the wave reads one
// contiguous 512B slice of h. (col,val) staged through LDS in chunks of 64.
__global__ __launch_bounds__(64) void aggregate(const int* __restrict__ offsets,
                                                const int2* __restrict__ sorted,
                                                const float2* __restrict__ h2,
                                                const float2* __restrict__ h02,
                                                float2* __restrict__ out2) {
    __shared__ int2 lds[64];
    int r = blockIdx.x;
    int t = threadIdx.x;
    int start = offsets[r];
    int end   = offsets[r + 1];
    float ax = 0.0f, ay = 0.0f;
    for (int base = start; base < end; base += 64) {
        int n = end - base;
        if (n > 64) n = 64;
        if (t < n) lds[t] = sorted[base + t];
        __syncthreads();
        for (int j = 0; j < n; ++j) {
            int c = lds[j].x;
            float v = __int_as_float(lds[j].y);
            float2 hc = h2[(size_t)c * HALF_D + t];
            ax = fmaf(v, hc.x, ax);
            ay = fmaf(v, hc.y, ay);
        }
        __syncthreads();
    }
    float2 g = h02[(size_t)r * HALF_D + t];
    float2 o;
    o.x = fmaf(0.9f, ax, 0.1f * g.x);
    o.y = fmaf(0.9f, ay, 0.1f * g.y);
    out2[(size_t)r * HALF_D + t] = o;
}

// ---------------- fallback (only if ws too small): atomic scatter ----------------

__global__ void init_out(const float* __restrict__ h0, float* __restrict__ out, int n) {
    int i = blockIdx.x * blockDim.x + threadIdx.x;
    if (i < n) out[i] = 0.1f * h0[i];
}

__global__ void scatter_atomic(const int* __restrict__ row, const int* __restrict__ col,
                               const float* __restrict__ val, const float* __restrict__ h,
                               float* __restrict__ out, int E) {
    long idx = (long)blockIdx.x * blockDim.x + threadIdx.x;
    int e = (int)(idx >> 6);
    if (e >= E) return;
    int t = (int)(idx & 63);
    int r = row[e], c = col[e];
    float v = 0.9f * val[e];
    atomicAdd(&out[(size_t)r * N_D + 2 * t],     v * h[(size_t)c * N_D + 2 * t]);
    atomicAdd(&out[(size_t)r * N_D + 2 * t + 1], v * h[(size_t)c * N_D + 2 * t + 1]);
}

extern "C" void kernel_launch(void* const* d_in, const int* in_sizes, int n_in,
                              void* d_out, int out_size, void* d_ws, size_t ws_size,
                              hipStream_t stream) {
    const int*   edge_row = (const int*)d_in[0];
    const int*   edge_col = (const int*)d_in[1];
    const float* edge_val = (const float*)d_in[2];
    const float* h        = (const float*)d_in[3];
    const float* h0       = (const float*)d_in[4];
    float*       out      = (float*)d_out;

    const int E = in_sizes[0];
    const int N = in_sizes[3] / N_D;

    // workspace layout (16B aligned regions)
    auto align16 = [](size_t x) { return (x + 15) & ~(size_t)15; };
    size_t counts_off  = 0;
    size_t offsets_off = align16(counts_off + (size_t)N * 4);
    size_t cursor_off  = align16(offsets_off + (size_t)(N + 1) * 4);
    size_t bsums_off   = align16(cursor_off + (size_t)N * 4);
    int    numBlocks   = (N + 1023) / 1024;
    size_t sorted_off  = align16(bsums_off + (size_t)numBlocks * 4);
    size_t total_ws    = sorted_off + (size_t)E * 8;

    char* ws = (char*)d_ws;
    if (ws_size >= total_ws && numBlocks <= 128) {
        int*  counts  = (int*)(ws + counts_off);
        int*  offsets = (int*)(ws + offsets_off);
        int*  cursor  = (int*)(ws + cursor_off);
        int*  bsums   = (int*)(ws + bsums_off);
        int2* sorted  = (int2*)(ws + sorted_off);

        hipMemsetAsync(counts, 0, (size_t)N * 4, stream);
        count_rows<<<(E + 255) / 256, 256, 0, stream>>>(edge_row, counts, E);
        scan_local<<<numBlocks, 1024, 0, stream>>>(counts, offsets, bsums, N);
        scan_blocksums<<<1, 128, 0, stream>>>(bsums, numBlocks);
        finalize_offsets<<<(N + 255) / 256, 256, 0, stream>>>(counts, offsets, bsums, cursor, N);
        scatter_edges<<<(E + 255) / 256, 256, 0, stream>>>(edge_row, edge_col, edge_val, cursor, sorted, E);
        aggregate<<<N, 64, 0, stream>>>(offsets, sorted,
                                        (const float2*)h, (const float2*)h0, (float2*)out);
    } else {
        // fallback: direct atomic scatter (correct but slower)
        int nd = N * N_D;
        init_out<<<(nd + 255) / 256, 256, 0, stream>>>(h0, out, nd);
        long total_threads = (long)E * 64;
        scatter_atomic<<<(int)((total_threads + 255) / 256), 256, 0, stream>>>(
            edge_row, edge_col, edge_val, h, out, E);
    }
}